// Round 7
// baseline (12.936 us; speedup 1.0000x reference)
//
#include <hip/hip_runtime.h>
#include <hip/hip_bf16.h>

#define HH 256
#define WW 256
#define NN 512
#define FXC 300.0f
#define FYC 300.0f
#define CXC 128.0f
#define CYC 128.0f
#define NEARC 0.01f
#define MAXRAD 20.0f

// Single fused kernel: one block (512 threads = 8 waves) per image row.
// Each block projects all 512 gaussians (1/thread, params kept in regs),
// ballot-compacts the ones touching its row FROM REGISTERS into a
// per-wave-segmented list (no extra barrier), sorts that short list by
// (depth desc, index asc) == stable argsort(-depths), and alpha-blends
// back-to-front. Two __syncthreads total.
//
// LDS per-gaussian params (by ORIGINAL index):
//  sq0 = {u, v, x0, x1}   sq1 = {y0, y1, neg_inv_2sig2, op}   sq2 = {r, g, b, depth}

__global__ __launch_bounds__(2 * WW) void fused_kernel(
    const float* __restrict__ pos,      // 512x3
    const float* __restrict__ scl,      // 512x3
    const float* __restrict__ col,      // 512x3
    const float* __restrict__ opac,     // 512
    const float* __restrict__ viewm,    // 16
    const float* __restrict__ bg,       // 3
    float* __restrict__ out)            // 3x256x256
{
    __shared__ float4 sq0[NN];
    __shared__ float4 sq1[NN];
    __shared__ float4 sq2[NN];
    __shared__ int    slist[NN];        // segmented: wave w -> [w*64, w*64+swave[w])
    __shared__ int    ssort[NN];        // selected, back-to-front order
    __shared__ int    swave[8];

    const int t = threadIdx.x;
    const int wave = t >> 6;
    const int lane = t & 63;
    const int y = blockIdx.x;
    const float yy = (float)y;

    // issue uniform loads early (latency hidden under Phase 0)
    const float bg0 = bg[0];
    const float bg1 = bg[1];
    const float bg2 = bg[2];

    float V[12];
    #pragma unroll
    for (int j = 0; j < 12; ++j) V[j] = viewm[j];

    // ---- Phase 0: project 1 gaussian per thread, params in registers ----
    {
        const int g = t;
        const float px = pos[g * 3 + 0], py = pos[g * 3 + 1], pz = pos[g * 3 + 2];
        const float s0 = scl[g * 3 + 0], s1 = scl[g * 3 + 1], s2 = scl[g * 3 + 2];
        const float c0 = col[g * 3 + 0], c1 = col[g * 3 + 1], c2 = col[g * 3 + 2];
        const float op = opac[g];

        const float cx = V[0] * px + V[1] * py + V[2]  * pz + V[3];
        const float cy = V[4] * px + V[5] * py + V[6]  * pz + V[7];
        const float cz = V[8] * px + V[9] * py + V[10] * pz + V[11];
        const float zs = cz + 1e-8f;
        const float sgn = (zs > 0.0f) ? 1.0f : ((zs < 0.0f) ? -1.0f : 0.0f);
        const float d = -(fmaxf(fabsf(cz), NEARC) * sgn);

        float u = 0.0f, v = 0.0f;
        float x0 = 1e9f, x1 = -1e9f, y0 = 1e9f, y1 = -1e9f;
        float neg_inv = 0.0f;
        if (d > 0.0f) {
            const float inv_d = 1.0f / d;
            u = FXC * cx * inv_d + CXC;
            v = CYC - FYC * cy * inv_d;
            const float sm = (s0 + s1 + s2) * (1.0f / 3.0f);
            float radius = floorf(sm * FXC * inv_d);
            radius = fminf(fmaxf(radius, 1.0f), MAXRAD);
            const float xi = truncf(u);
            const float yi = truncf(v);
            x0 = fmaxf(0.0f, xi - radius);
            x1 = fminf((float)WW, xi + radius + 1.0f);
            y0 = fmaxf(0.0f, yi - radius);
            y1 = fminf((float)HH, yi + radius + 1.0f);
            const float sigma = fmaxf(radius * 0.5f, 1.0f);
            neg_inv = -1.0f / (2.0f * sigma * sigma);
        }
        sq0[g] = make_float4(u, v, x0, x1);
        sq1[g] = make_float4(y0, y1, neg_inv, op);
        sq2[g] = make_float4(c0, c1, c2, d);

        // ---- Phase 1 (fused): row test straight from registers ----
        const bool fa = (yy >= y0) && (yy < y1);     // d<=0 => y0=1e9 => false
        const unsigned long long ba = __ballot(fa);
        if (lane == 0) swave[wave] = __popcll(ba);
        if (fa) slist[wave * 64 + __popcll(ba & ((1ull << lane) - 1ull))] = t;
    }
    __syncthreads();

    // per-thread copy of segment counts (broadcast LDS reads)
    int cnt[8];
    #pragma unroll
    for (int w = 0; w < 8; ++w) cnt[w] = swave[w];
    const int M = cnt[0] + cnt[1] + cnt[2] + cnt[3]
                + cnt[4] + cnt[5] + cnt[6] + cnt[7];

    // ---- Phase 2: sort the selected list back-to-front ----
    // key: depth desc, original index asc (== stable argsort(-depths)).
    if (t < M) {
        // locate element t in the segmented list
        int tt = t, w = 0;
        while (tt >= cnt[w]) { tt -= cnt[w]; ++w; }
        const int gi = slist[w * 64 + tt];
        const float di = sq2[gi].w;
        int r = 0;
        for (int w2 = 0; w2 < 8; ++w2) {
            const int c2 = cnt[w2];
            for (int j = 0; j < c2; ++j) {
                const int gj = slist[w2 * 64 + j];
                const float dj = sq2[gj].w;
                r += (dj > di) | ((dj == di) & (gj < gi));
            }
        }
        ssort[r] = gi;
    }
    __syncthreads();

    // ---- Phase 3: per-pixel ordered blend (threads 0..255 = pixels) ----
    if (t < WW) {
        const float xx = (float)t;
        float cr = bg0;
        float cg = bg1;
        float cb = bg2;

        for (int i = 0; i < M; ++i) {
            const int gi = ssort[i];        // uniform -> broadcast reads
            const float4 q0 = sq0[gi];
            float a = 0.0f;
            if (xx >= q0.z && xx < q0.w) {
                const float4 q1 = sq1[gi];
                const float dx = xx - q0.x;
                const float dy = yy - q0.y;
                a = __expf((dx * dx + dy * dy) * q1.z) * q1.w;
                a = fminf(fmaxf(a, 0.0f), 1.0f);
            }
            const float4 q2 = sq2[gi];
            const float one_m = 1.0f - a;
            cr = a * q2.x + one_m * cr;
            cg = a * q2.y + one_m * cg;
            cb = a * q2.z + one_m * cb;
        }

        const int pix = y * WW + t;
        out[0 * HH * WW + pix] = cr;
        out[1 * HH * WW + pix] = cg;
        out[2 * HH * WW + pix] = cb;
    }
}

extern "C" void kernel_launch(void* const* d_in, const int* in_sizes, int n_in,
                              void* d_out, int out_size, void* d_ws, size_t ws_size,
                              hipStream_t stream) {
    const float* positions  = (const float*)d_in[0];
    const float* scales     = (const float*)d_in[1];
    // d_in[2] = rotations (unused by reference)
    const float* colors     = (const float*)d_in[3];
    const float* opacities  = (const float*)d_in[4];
    const float* view_matrix= (const float*)d_in[5];
    const float* background = (const float*)d_in[6];

    fused_kernel<<<HH, 2 * WW, 0, stream>>>(positions, scales, colors, opacities,
                                            view_matrix, background, (float*)d_out);
}

// Round 8
// 11.949 us; speedup vs baseline: 1.0826x; 1.0826x over previous
//
#include <hip/hip_runtime.h>
#include <hip/hip_bf16.h>

#define HH 256
#define WW 256
#define NN 512
#define FXC 300.0f
#define FYC 300.0f
#define CXC 128.0f
#define CYC 128.0f
#define NEARC 0.01f
#define MAXRAD 20.0f

// Single fused kernel: one block (512 threads = 8 waves) per image row.
// Each block projects all 512 gaussians (1/thread, row-test balloted from
// registers), compacts the ones touching its row into a contiguous list
// (M ~ 18, ascending original index), sorts that list by (depth desc,
// index asc) == stable argsort(-depths), and alpha-blends back-to-front.
// 3 __syncthreads total; sort is the simple R6 form (no divergent locate).
//
// LDS per-gaussian params (by ORIGINAL index):
//  sq0 = {u, v, x0, x1}   sq1 = {y0, y1, neg_inv_2sig2, op}   sq2 = {r, g, b, depth}

__global__ __launch_bounds__(2 * WW) void fused_kernel(
    const float* __restrict__ pos,      // 512x3
    const float* __restrict__ scl,      // 512x3
    const float* __restrict__ col,      // 512x3
    const float* __restrict__ opac,     // 512
    const float* __restrict__ viewm,    // 16
    const float* __restrict__ bg,       // 3
    float* __restrict__ out)            // 3x256x256
{
    __shared__ float4 sq0[NN];
    __shared__ float4 sq1[NN];
    __shared__ float4 sq2[NN];
    __shared__ int    slist[NN];        // selected, ascending original index
    __shared__ int    ssort[NN];        // selected, back-to-front order
    __shared__ int    swave[8];

    const int t = threadIdx.x;
    const int wave = t >> 6;
    const int lane = t & 63;
    const int y = blockIdx.x;
    const float yy = (float)y;

    // issue uniform loads early (latency hidden under Phase 0)
    const float bg0 = bg[0];
    const float bg1 = bg[1];
    const float bg2 = bg[2];

    float V[12];
    #pragma unroll
    for (int j = 0; j < 12; ++j) V[j] = viewm[j];

    // ---- Phase 0: project 1 gaussian per thread; row-test from registers ----
    bool fa;
    int  myrank;
    {
        const int g = t;
        const float px = pos[g * 3 + 0], py = pos[g * 3 + 1], pz = pos[g * 3 + 2];
        const float s0 = scl[g * 3 + 0], s1 = scl[g * 3 + 1], s2 = scl[g * 3 + 2];
        const float c0 = col[g * 3 + 0], c1 = col[g * 3 + 1], c2 = col[g * 3 + 2];
        const float op = opac[g];

        const float cx = V[0] * px + V[1] * py + V[2]  * pz + V[3];
        const float cy = V[4] * px + V[5] * py + V[6]  * pz + V[7];
        const float cz = V[8] * px + V[9] * py + V[10] * pz + V[11];
        const float zs = cz + 1e-8f;
        const float sgn = (zs > 0.0f) ? 1.0f : ((zs < 0.0f) ? -1.0f : 0.0f);
        const float d = -(fmaxf(fabsf(cz), NEARC) * sgn);

        float u = 0.0f, v = 0.0f;
        float x0 = 1e9f, x1 = -1e9f, y0 = 1e9f, y1 = -1e9f;
        float neg_inv = 0.0f;
        if (d > 0.0f) {
            const float inv_d = 1.0f / d;
            u = FXC * cx * inv_d + CXC;
            v = CYC - FYC * cy * inv_d;
            const float sm = (s0 + s1 + s2) * (1.0f / 3.0f);
            float radius = floorf(sm * FXC * inv_d);
            radius = fminf(fmaxf(radius, 1.0f), MAXRAD);
            const float xi = truncf(u);
            const float yi = truncf(v);
            x0 = fmaxf(0.0f, xi - radius);
            x1 = fminf((float)WW, xi + radius + 1.0f);
            y0 = fmaxf(0.0f, yi - radius);
            y1 = fminf((float)HH, yi + radius + 1.0f);
            const float sigma = fmaxf(radius * 0.5f, 1.0f);
            neg_inv = -1.0f / (2.0f * sigma * sigma);
        }
        sq0[g] = make_float4(u, v, x0, x1);
        sq1[g] = make_float4(y0, y1, neg_inv, op);
        sq2[g] = make_float4(c0, c1, c2, d);

        fa = (yy >= y0) && (yy < y1);       // d<=0 => y0=1e9 => false
        const unsigned long long ba = __ballot(fa);
        if (lane == 0) swave[wave] = __popcll(ba);
        myrank = __popcll(ba & ((1ull << lane) - 1ull));
    }
    __syncthreads();

    // ---- Phase 1: contiguous compaction (ascending original index) ----
    int base = 0;
    #pragma unroll
    for (int w = 0; w < 8; ++w) base += (w < wave) ? swave[w] : 0;
    const int M = swave[0] + swave[1] + swave[2] + swave[3]
                + swave[4] + swave[5] + swave[6] + swave[7];
    if (fa) slist[base + myrank] = t;
    __syncthreads();

    // ---- Phase 2: sort the selected list back-to-front ----
    // key: depth desc, original index asc (== stable argsort(-depths)).
    if (t < M) {
        const int gi = slist[t];
        const float di = sq2[gi].w;
        int r = 0;
        for (int j = 0; j < M; ++j) {
            const int gj = slist[j];
            const float dj = sq2[gj].w;
            r += (dj > di) | ((dj == di) & (gj < gi));
        }
        ssort[r] = gi;
    }
    __syncthreads();

    // ---- Phase 3: per-pixel ordered blend (threads 0..255 = pixels) ----
    if (t < WW) {
        const float xx = (float)t;
        float cr = bg0;
        float cg = bg1;
        float cb = bg2;

        for (int i = 0; i < M; ++i) {
            const int gi = ssort[i];        // uniform -> broadcast reads
            const float4 q0 = sq0[gi];
            float a = 0.0f;
            if (xx >= q0.z && xx < q0.w) {
                const float4 q1 = sq1[gi];
                const float dx = xx - q0.x;
                const float dy = yy - q0.y;
                a = __expf((dx * dx + dy * dy) * q1.z) * q1.w;
                a = fminf(fmaxf(a, 0.0f), 1.0f);
            }
            const float4 q2 = sq2[gi];
            const float one_m = 1.0f - a;
            cr = a * q2.x + one_m * cr;
            cg = a * q2.y + one_m * cg;
            cb = a * q2.z + one_m * cb;
        }

        const int pix = y * WW + t;
        out[0 * HH * WW + pix] = cr;
        out[1 * HH * WW + pix] = cg;
        out[2 * HH * WW + pix] = cb;
    }
}

extern "C" void kernel_launch(void* const* d_in, const int* in_sizes, int n_in,
                              void* d_out, int out_size, void* d_ws, size_t ws_size,
                              hipStream_t stream) {
    const float* positions  = (const float*)d_in[0];
    const float* scales     = (const float*)d_in[1];
    // d_in[2] = rotations (unused by reference)
    const float* colors     = (const float*)d_in[3];
    const float* opacities  = (const float*)d_in[4];
    const float* view_matrix= (const float*)d_in[5];
    const float* background = (const float*)d_in[6];

    fused_kernel<<<HH, 2 * WW, 0, stream>>>(positions, scales, colors, opacities,
                                            view_matrix, background, (float*)d_out);
}